// Round 8
// baseline (536.297 us; speedup 1.0000x reference)
//
#include <hip/hip_runtime.h>

#define N_NODES 100000
#define N_PAD 100032      // padded to 64-node tiles for MFMA sizematch
#define N_EDGES 1600000
#define NUM_RELS 8
#define KDIM 256      // E_DIM * MAX_LEN
#define HD 64
#define KF 512        // fused GEMM K = NUM_RELS * 64

// CSR-build partition parameters: 256-node coarse buckets
#define B_SHIFT 8
#define NBUCK 392         // ceil(100000/256)=391, +1 pad
#define NBUCK_USED 391
#define NBLK_P 512
#define TPB_P 256
#define EPB 3125          // 512 * 3125 = 1.6M exactly

typedef __attribute__((ext_vector_type(8))) short bf16x8;
typedef __attribute__((ext_vector_type(4))) float f32x4;

__device__ inline unsigned short f2bf(float f) {
    unsigned u = __float_as_uint(f);
    u += 0x7fff + ((u >> 16) & 1);   // round-to-nearest-even
    return (unsigned short)(u >> 16);
}
__device__ inline float bf2f(unsigned short s) {
    return __uint_as_float(((unsigned)s) << 16);
}
__device__ inline unsigned packtrunc(float x, float y) {
    return (__float_as_uint(x) >> 16) | (__float_as_uint(y) & 0xffff0000u);
}

// ---------------- weights:
//  WpF_l: B-fragment layout over K=512: WpF[((s*4+q)*64+o)*8+j] = Wfull[kk=s*32+q*8+j][o]
//  where Wfull[r*64+k][o] = sum_b comp[r,b] V[b,k,o]
//  smPack: B-fragment layout for size matcher (K=256)
__global__ void k_weights(const float* __restrict__ V1, const float* __restrict__ comp1,
                          const float* __restrict__ V2, const float* __restrict__ comp2,
                          const float* __restrict__ sm_w,
                          unsigned short* __restrict__ WpF1, unsigned short* __restrict__ WpF2,
                          unsigned short* __restrict__ smPack) {
    int idx = blockIdx.x * 256 + threadIdx.x;
    if (idx < 2 * NUM_RELS * 64 * 64) {
        int l = idx >> 15;
        int r = (idx >> 12) & 7;
        int k = (idx >> 6) & 63;
        int o = idx & 63;
        const float* V = l ? V2 : V1;
        const float* comp = l ? comp2 : comp1;
        float s = 0.f;
#pragma unroll
        for (int b = 0; b < 8; b++) s += comp[r * 8 + b] * V[(b * 64 + k) * 64 + o];
        int kk = r * 64 + k;
        int ss = kk >> 5, q = (kk >> 3) & 3, j = kk & 7;
        unsigned short* Wp = l ? WpF2 : WpF1;
        Wp[(((ss * 4 + q) * 64) + o) * 8 + j] = f2bf(s);
    } else {
        int j = idx - 65536;
        if (j < KDIM * HD) {
            int k = j >> 6, o = j & 63;
            int s = k >> 5, q = (k >> 3) & 3, jj = k & 7;
            smPack[(((s * 4 + q) * 64) + o) * 8 + jj] = f2bf(sm_w[o * KDIM + k]);
        }
    }
}

// ---------------- pass A: per-block LDS histogram over coarse buckets
__launch_bounds__(TPB_P)
__global__ void k_pcount(const int* __restrict__ dst, int* __restrict__ cnt) {
    __shared__ int lh[NBUCK];
    int t = threadIdx.x, blk = blockIdx.x;
    for (int b = t; b < NBUCK; b += TPB_P) lh[b] = 0;
    __syncthreads();
    int base = blk * EPB;
    for (int i = t; i < EPB; i += TPB_P) atomicAdd(&lh[dst[base + i] >> B_SHIFT], 1);
    __syncthreads();
    for (int b = t; b < NBUCK; b += TPB_P) cnt[blk * NBUCK + b] = lh[b];
}

// ---------------- pass B1: per-bucket exclusive scan across the NBLK_P blocks
__launch_bounds__(NBLK_P)
__global__ void k_pscan(const int* __restrict__ cnt, int* __restrict__ boffm, int* __restrict__ btot) {
    __shared__ int s[NBLK_P];
    int b = blockIdx.x, t = threadIdx.x;
    int v = cnt[t * NBUCK + b];
    s[t] = v;
    __syncthreads();
    for (int off = 1; off < NBLK_P; off <<= 1) {
        int u = (t >= off) ? s[t - off] : 0;
        __syncthreads();
        s[t] += u;
        __syncthreads();
    }
    boffm[t * NBUCK + b] = s[t] - v;
    if (t == NBLK_P - 1) btot[b] = s[NBLK_P - 1];
}

// ---------------- pass B2: exclusive scan over bucket totals -> bucket starts; sentinel
__launch_bounds__(512)
__global__ void k_bscan(const int* __restrict__ btot, int* __restrict__ bstart, int* __restrict__ rowptr8) {
    __shared__ int s[512];
    int t = threadIdx.x;
    int v = (t < NBUCK_USED) ? btot[t] : 0;
    s[t] = v;
    __syncthreads();
    for (int off = 1; off < 512; off <<= 1) {
        int u = (t >= off) ? s[t - off] : 0;
        __syncthreads();
        s[t] += u;
        __syncthreads();
    }
    bstart[t] = s[t] - v;
    if (t == 0) rowptr8[(size_t)N_NODES * 8] = N_EDGES;
}

// ---------------- pass C: scatter edges into bucket-contiguous staging
// packed = src | et<<17 | dlocal<<20  -> key = (packed>>17)&2047 = dlocal*8+et
__launch_bounds__(TPB_P)
__global__ void k_pscatter(const int* __restrict__ src, const int* __restrict__ dst,
                           const int* __restrict__ et, const float* __restrict__ norm,
                           const int* __restrict__ boffm, const int* __restrict__ bstart,
                           int2* __restrict__ staged) {
    __shared__ int ldsoff[NBUCK];
    int t = threadIdx.x, blk = blockIdx.x;
    for (int b = t; b < NBUCK; b += TPB_P) ldsoff[b] = bstart[b] + boffm[blk * NBUCK + b];
    __syncthreads();
    int base = blk * EPB;
    for (int i = t; i < EPB; i += TPB_P) {
        int e = base + i;
        int d = dst[e];
        int bu = d >> B_SHIFT;
        int pos = atomicAdd(&ldsoff[bu], 1);
        int packed = src[e] | (et[e] << 17) | ((d & 255) << 20);
        staged[pos] = make_int2(packed, __float_as_int(norm[e]));
    }
}

// ---------------- pass D: per-bucket 2048-bin counting sort -> rowptr8 + sorted edata
__launch_bounds__(512)
__global__ void k_finalize(const int2* __restrict__ staged, const int* __restrict__ bstart,
                           const int* __restrict__ btot, int* __restrict__ rowptr8,
                           int2* __restrict__ edata) {
    __shared__ int lh[2048];
    __shared__ int s512[512];
    __shared__ int lsc[2048];
    int b = blockIdx.x, t = threadIdx.x;
    int base = bstart[b];
    int cnt = btot[b];
    lh[t] = 0; lh[t + 512] = 0; lh[t + 1024] = 0; lh[t + 1536] = 0;
    __syncthreads();
    int2 held[9];
    int key[9], rank[9];
    int nh = 0;
    for (int i = t; i < cnt; i += 512) {
        int2 ed = staged[base + i];
        int k = (ed.x >> 17) & 2047;
        held[nh] = ed; key[nh] = k; rank[nh] = atomicAdd(&lh[k], 1); nh++;
    }
    __syncthreads();
    int b0 = lh[t * 4], b1 = lh[t * 4 + 1], b2 = lh[t * 4 + 2], b3 = lh[t * 4 + 3];
    int tot = b0 + b1 + b2 + b3;
    s512[t] = tot;
    __syncthreads();
    for (int off = 1; off < 512; off <<= 1) {
        int u = (t >= off) ? s512[t - off] : 0;
        __syncthreads();
        s512[t] += u;
        __syncthreads();
    }
    int excl = s512[t] - tot;
    lsc[t * 4] = excl;
    lsc[t * 4 + 1] = excl + b0;
    lsc[t * 4 + 2] = excl + b0 + b1;
    lsc[t * 4 + 3] = excl + b0 + b1 + b2;
    __syncthreads();
    // rowptr8 for this bucket: global idx = (b<<11) + (dlocal*8+et) — contiguous
    int limit = (N_NODES << 3) - (b << 11);
    for (int idx = t; idx < 2048; idx += 512)
        if (idx < limit) rowptr8[(b << 11) + idx] = base + lsc[idx];
    for (int i = 0; i < nh; i++) {
        int p = base + lsc[key[i]] + rank[i];
        edata[p] = make_int2(held[i].x & 0x1FFFF, held[i].y);   // {src, norm_bits}
    }
}

// ---------------- size matcher (MFMA, no LDS)
__launch_bounds__(256)
__global__ void k_sizematch(const int* __restrict__ feat, const float* __restrict__ emb_w,
                            const unsigned short* __restrict__ smPack, const float* __restrict__ sm_b,
                            unsigned short* __restrict__ xb) {
    int t = threadIdx.x;
    int wave = t >> 6, lane = t & 63;
    int q = lane >> 4, c = lane & 15;
    int n0 = blockIdx.x * 64 + wave * 16;
    int node = n0 + c;
    int nclamp = (node < N_NODES) ? node : (N_NODES - 1);
    const int4* fr = (const int4*)(feat + (size_t)nclamp * 8);
    int4 f0 = fr[0], f1 = fr[1];
    int fidx[8] = {f0.x, f0.y, f0.z, f0.w, f1.x, f1.y, f1.z, f1.w};
    f32x4 acc[4];
#pragma unroll
    for (int i = 0; i < 4; i++) acc[i] = (f32x4){0.f, 0.f, 0.f, 0.f};
    const bf16x8* B8 = (const bf16x8*)smPack;
#pragma unroll
    for (int s = 0; s < 8; s++) {
        const float4* ar = (const float4*)(emb_w + (size_t)fidx[s] * 32 + q * 8);
        float4 a0 = ar[0], a1 = ar[1];
        union { unsigned u[4]; bf16x8 v; } A;
        A.u[0] = packtrunc(a0.x, a0.y);
        A.u[1] = packtrunc(a0.z, a0.w);
        A.u[2] = packtrunc(a1.x, a1.y);
        A.u[3] = packtrunc(a1.z, a1.w);
#pragma unroll
        for (int tl = 0; tl < 4; tl++) {
            bf16x8 b = B8[(s * 4 + q) * 64 + tl * 16 + c];
            acc[tl] = __builtin_amdgcn_mfma_f32_16x16x32_bf16(A.v, b, acc[tl], 0, 0, 0);
        }
    }
    int row_base = n0 + q * 4;
    bool full = (n0 + 15 < N_NODES);
#pragma unroll
    for (int tl = 0; tl < 4; tl++) {
        int o = tl * 16 + c;
        float bia = sm_b[o];
#pragma unroll
        for (int r = 0; r < 4; r++) {
            int nd = row_base + r;
            if (full || nd < N_NODES)
                xb[(size_t)nd * 64 + o] = f2bf(acc[tl][r] + bia);
        }
    }
}

// ---------------- fused layer: branch-free per-(node,rel) segment aggregation + MFMA
// block: 256 thr = 4 waves; 16 nodes/block (4 per wave); grid N_NODES/16.
__launch_bounds__(256)
__global__ void k_fused(const unsigned short* __restrict__ xin,
                        const int* __restrict__ rowptr8, const int2* __restrict__ edata,
                        const unsigned short* __restrict__ WpF, const float* __restrict__ bias,
                        float* __restrict__ outf, unsigned short* __restrict__ outb, int mode) {
    __shared__ __align__(16) unsigned short agg[16 * 520];
    int t = threadIdx.x;
    int wave = t >> 6, lane = t & 63;
    int n0 = blockIdx.x * 16;
    for (int ni = 0; ni < 4; ni++) {
        int lrow = wave * 4 + ni;
        int node = n0 + lrow;
        const int* rp = rowptr8 + (size_t)node * 8;
        int j1 = rp[0];
#pragma unroll 1
        for (int r = 0; r < 8; r++) {
            int j0 = j1;
            j1 = rp[r + 1];        // rp[8] == next node's rel-0 start (contiguous)
            float acc = 0.f;
            int j = j0;
            for (; j + 4 <= j1; j += 4) {
                int2 e0 = edata[j], e1 = edata[j + 1], e2 = edata[j + 2], e3 = edata[j + 3];
                float v0 = bf2f(xin[((size_t)e0.x << 6) + lane]);
                float v1 = bf2f(xin[((size_t)e1.x << 6) + lane]);
                float v2 = bf2f(xin[((size_t)e2.x << 6) + lane]);
                float v3 = bf2f(xin[((size_t)e3.x << 6) + lane]);
                acc += __int_as_float(e0.y) * v0;
                acc += __int_as_float(e1.y) * v1;
                acc += __int_as_float(e2.y) * v2;
                acc += __int_as_float(e3.y) * v3;
            }
            for (; j < j1; j++) {
                int2 e = edata[j];
                float v = bf2f(xin[((size_t)e.x << 6) + lane]);
                acc += __int_as_float(e.y) * v;
            }
            agg[lrow * 520 + r * 64 + lane] = f2bf(acc);
        }
    }
    __syncthreads();
    // ---- MFMA: [16 nodes x 512] @ WpF -> 64 outs; wave covers cols [wave*16, +16)
    int q = lane >> 4, c = lane & 15;
    int o16 = wave * 16;
    f32x4 accd = (f32x4){0.f, 0.f, 0.f, 0.f};
    const bf16x8* B8 = (const bf16x8*)WpF;
#pragma unroll
    for (int s = 0; s < 16; s++) {
        bf16x8 a = *(const bf16x8*)&agg[c * 520 + s * 32 + q * 8];
        bf16x8 bfr = B8[(s * 4 + q) * 64 + o16 + c];
        accd = __builtin_amdgcn_mfma_f32_16x16x32_bf16(a, bfr, accd, 0, 0, 0);
    }
    int col = o16 + c;
    float bia = bias[col];
#pragma unroll
    for (int r = 0; r < 4; r++) {
        int node = n0 + q * 4 + r;
        float v = accd[r] + bia;
        if (mode == 1) {
            v = fmaxf(v, 0.f);
            outb[(size_t)node * 64 + col] = f2bf(v);
        } else {
            outf[(size_t)node * 64 + col] = v;
        }
    }
}

extern "C" void kernel_launch(void* const* d_in, const int* in_sizes, int n_in,
                              void* d_out, int out_size, void* d_ws, size_t ws_size,
                              hipStream_t stream) {
    const int*   feat  = (const int*)d_in[0];
    const int*   src   = (const int*)d_in[1];
    const int*   dst   = (const int*)d_in[2];
    const int*   etype = (const int*)d_in[3];
    const float* norm  = (const float*)d_in[4];
    const float* emb_w = (const float*)d_in[5];
    const float* sm_w  = (const float*)d_in[6];
    const float* sm_b  = (const float*)d_in[7];
    const float* V1    = (const float*)d_in[8];
    const float* comp1 = (const float*)d_in[9];
    const float* b1    = (const float*)d_in[10];
    const float* V2    = (const float*)d_in[11];
    const float* comp2 = (const float*)d_in[12];
    const float* b2    = (const float*)d_in[13];
    float* out = (float*)d_out;

    char* p = (char*)d_ws;
    auto alloc = [&](size_t bytes) { void* q = (void*)p; p += (bytes + 255) & ~(size_t)255; return q; };
    unsigned short* xb   = (unsigned short*)alloc((size_t)N_PAD * 64 * 2);  // 12.8 MB
    unsigned short* hb   = (unsigned short*)alloc((size_t)N_PAD * 64 * 2);  // 12.8 MB
    unsigned short* WpF1 = (unsigned short*)alloc((size_t)KF * HD * 2);     // 64 KB
    unsigned short* WpF2 = (unsigned short*)alloc((size_t)KF * HD * 2);
    unsigned short* smPack = (unsigned short*)alloc(KDIM * HD * 2);         // 32 KB
    int*   cnt    = (int*)alloc((size_t)NBLK_P * NBUCK * 4);                // 803 KB
    int*   boffm  = (int*)alloc((size_t)NBLK_P * NBUCK * 4);                // 803 KB
    int*   btot   = (int*)alloc((size_t)NBUCK * 4);
    int*   bstart = (int*)alloc((size_t)(NBUCK + 1) * 4);
    int*   rowptr8 = (int*)alloc(((size_t)N_NODES * 8 + 1) * 4);            // 3.2 MB
    int2*  staged = (int2*)alloc((size_t)N_EDGES * 8);                      // 12.8 MB
    int2*  edata  = (int2*)alloc((size_t)N_EDGES * 8);                      // 12.8 MB

    k_weights<<<320, 256, 0, stream>>>(V1, comp1, V2, comp2, sm_w, WpF1, WpF2, smPack);

    k_pcount<<<NBLK_P, TPB_P, 0, stream>>>(dst, cnt);
    k_pscan<<<NBUCK_USED, NBLK_P, 0, stream>>>(cnt, boffm, btot);
    k_bscan<<<1, 512, 0, stream>>>(btot, bstart, rowptr8);
    k_pscatter<<<NBLK_P, TPB_P, 0, stream>>>(src, dst, etype, norm, boffm, bstart, staged);
    k_finalize<<<NBUCK_USED, 512, 0, stream>>>(staged, bstart, btot, rowptr8, edata);

    k_sizematch<<<N_PAD / 64, 256, 0, stream>>>(feat, emb_w, smPack, sm_b, xb);

    k_fused<<<N_NODES / 16, 256, 0, stream>>>(xb, rowptr8, edata, WpF1, b1, nullptr, hb, 1);
    k_fused<<<N_NODES / 16, 256, 0, stream>>>(hb, rowptr8, edata, WpF2, b2, out, nullptr, 0);
}

// Round 9
// 363.069 us; speedup vs baseline: 1.4771x; 1.4771x over previous
//
#include <hip/hip_runtime.h>

#define N_NODES 100000
#define N_PAD 100032      // padded to 64-node tiles for MFMA sizematch
#define N_EDGES 1600000
#define NUM_RELS 8
#define KDIM 256      // E_DIM * MAX_LEN
#define HD 64
#define KF 512        // fused GEMM K = NUM_RELS * 64

// CSR-build partition parameters: 256-node coarse buckets
#define B_SHIFT 8
#define NBUCK 392         // ceil(100000/256)=391, +1 pad
#define NBUCK_USED 391
#define NBLK_P 512
#define TPB_P 256
#define EPB 3125          // 512 * 3125 = 1.6M exactly

typedef __attribute__((ext_vector_type(8))) short bf16x8;
typedef __attribute__((ext_vector_type(4))) float f32x4;

__device__ inline unsigned short f2bf(float f) {
    unsigned u = __float_as_uint(f);
    u += 0x7fff + ((u >> 16) & 1);   // round-to-nearest-even
    return (unsigned short)(u >> 16);
}
__device__ inline float bf2f(unsigned short s) {
    return __uint_as_float(((unsigned)s) << 16);
}
__device__ inline unsigned packtrunc(float x, float y) {
    return (__float_as_uint(x) >> 16) | (__float_as_uint(y) & 0xffff0000u);
}

// ---------------- weights:
//  WpF_l: B-fragment layout over K=512: WpF[((s*4+q)*64+o)*8+j] = Wfull[kk=s*32+q*8+j][o]
//  where Wfull[r*64+k][o] = sum_b comp[r,b] V[b,k,o]
//  smPack: B-fragment layout for size matcher (K=256)
__global__ void k_weights(const float* __restrict__ V1, const float* __restrict__ comp1,
                          const float* __restrict__ V2, const float* __restrict__ comp2,
                          const float* __restrict__ sm_w,
                          unsigned short* __restrict__ WpF1, unsigned short* __restrict__ WpF2,
                          unsigned short* __restrict__ smPack) {
    int idx = blockIdx.x * 256 + threadIdx.x;
    if (idx < 2 * NUM_RELS * 64 * 64) {
        int l = idx >> 15;
        int r = (idx >> 12) & 7;
        int k = (idx >> 6) & 63;
        int o = idx & 63;
        const float* V = l ? V2 : V1;
        const float* comp = l ? comp2 : comp1;
        float s = 0.f;
#pragma unroll
        for (int b = 0; b < 8; b++) s += comp[r * 8 + b] * V[(b * 64 + k) * 64 + o];
        int kk = r * 64 + k;
        int ss = kk >> 5, q = (kk >> 3) & 3, j = kk & 7;
        unsigned short* Wp = l ? WpF2 : WpF1;
        Wp[(((ss * 4 + q) * 64) + o) * 8 + j] = f2bf(s);
    } else {
        int j = idx - 65536;
        if (j < KDIM * HD) {
            int k = j >> 6, o = j & 63;
            int s = k >> 5, q = (k >> 3) & 3, jj = k & 7;
            smPack[(((s * 4 + q) * 64) + o) * 8 + jj] = f2bf(sm_w[o * KDIM + k]);
        }
    }
}

// ---------------- pass A: per-block LDS histogram over coarse buckets
__launch_bounds__(TPB_P)
__global__ void k_pcount(const int* __restrict__ dst, int* __restrict__ cnt) {
    __shared__ int lh[NBUCK];
    int t = threadIdx.x, blk = blockIdx.x;
    for (int b = t; b < NBUCK; b += TPB_P) lh[b] = 0;
    __syncthreads();
    int base = blk * EPB;
    for (int i = t; i < EPB; i += TPB_P) atomicAdd(&lh[dst[base + i] >> B_SHIFT], 1);
    __syncthreads();
    for (int b = t; b < NBUCK; b += TPB_P) cnt[blk * NBUCK + b] = lh[b];
}

// ---------------- pass B1: per-bucket exclusive scan across the NBLK_P blocks
__launch_bounds__(NBLK_P)
__global__ void k_pscan(const int* __restrict__ cnt, int* __restrict__ boffm, int* __restrict__ btot) {
    __shared__ int s[NBLK_P];
    int b = blockIdx.x, t = threadIdx.x;
    int v = cnt[t * NBUCK + b];
    s[t] = v;
    __syncthreads();
    for (int off = 1; off < NBLK_P; off <<= 1) {
        int u = (t >= off) ? s[t - off] : 0;
        __syncthreads();
        s[t] += u;
        __syncthreads();
    }
    boffm[t * NBUCK + b] = s[t] - v;
    if (t == NBLK_P - 1) btot[b] = s[NBLK_P - 1];
}

// ---------------- pass B2: exclusive scan over bucket totals -> bucket starts; sentinel
__launch_bounds__(512)
__global__ void k_bscan(const int* __restrict__ btot, int* __restrict__ bstart, int* __restrict__ rowptr8) {
    __shared__ int s[512];
    int t = threadIdx.x;
    int v = (t < NBUCK_USED) ? btot[t] : 0;
    s[t] = v;
    __syncthreads();
    for (int off = 1; off < 512; off <<= 1) {
        int u = (t >= off) ? s[t - off] : 0;
        __syncthreads();
        s[t] += u;
        __syncthreads();
    }
    bstart[t] = s[t] - v;
    if (t == 0) rowptr8[(size_t)N_NODES * 8] = N_EDGES;
}

// ---------------- pass C: scatter edges into bucket-contiguous staging
// packed = src | et<<17 | dlocal<<20  -> key = (packed>>17)&2047 = dlocal*8+et
__launch_bounds__(TPB_P)
__global__ void k_pscatter(const int* __restrict__ src, const int* __restrict__ dst,
                           const int* __restrict__ et, const float* __restrict__ norm,
                           const int* __restrict__ boffm, const int* __restrict__ bstart,
                           int2* __restrict__ staged) {
    __shared__ int ldsoff[NBUCK];
    int t = threadIdx.x, blk = blockIdx.x;
    for (int b = t; b < NBUCK; b += TPB_P) ldsoff[b] = bstart[b] + boffm[blk * NBUCK + b];
    __syncthreads();
    int base = blk * EPB;
    for (int i = t; i < EPB; i += TPB_P) {
        int e = base + i;
        int d = dst[e];
        int bu = d >> B_SHIFT;
        int pos = atomicAdd(&ldsoff[bu], 1);
        int packed = src[e] | (et[e] << 17) | ((d & 255) << 20);
        staged[pos] = make_int2(packed, __float_as_int(norm[e]));
    }
}

// ---------------- pass D: per-bucket 2048-bin counting sort -> rowptr8 + sorted edata
// edata keeps src | et<<17 (et needed by k_fused's flush logic)
__launch_bounds__(512)
__global__ void k_finalize(const int2* __restrict__ staged, const int* __restrict__ bstart,
                           const int* __restrict__ btot, int* __restrict__ rowptr8,
                           int2* __restrict__ edata) {
    __shared__ int lh[2048];
    __shared__ int s512[512];
    __shared__ int lsc[2048];
    int b = blockIdx.x, t = threadIdx.x;
    int base = bstart[b];
    int cnt = btot[b];
    lh[t] = 0; lh[t + 512] = 0; lh[t + 1024] = 0; lh[t + 1536] = 0;
    __syncthreads();
    int2 held[9];
    int key[9], rank[9];
    int nh = 0;
    for (int i = t; i < cnt; i += 512) {
        int2 ed = staged[base + i];
        int k = (ed.x >> 17) & 2047;
        held[nh] = ed; key[nh] = k; rank[nh] = atomicAdd(&lh[k], 1); nh++;
    }
    __syncthreads();
    int b0 = lh[t * 4], b1 = lh[t * 4 + 1], b2 = lh[t * 4 + 2], b3 = lh[t * 4 + 3];
    int tot = b0 + b1 + b2 + b3;
    s512[t] = tot;
    __syncthreads();
    for (int off = 1; off < 512; off <<= 1) {
        int u = (t >= off) ? s512[t - off] : 0;
        __syncthreads();
        s512[t] += u;
        __syncthreads();
    }
    int excl = s512[t] - tot;
    lsc[t * 4] = excl;
    lsc[t * 4 + 1] = excl + b0;
    lsc[t * 4 + 2] = excl + b0 + b1;
    lsc[t * 4 + 3] = excl + b0 + b1 + b2;
    __syncthreads();
    int limit = (N_NODES << 3) - (b << 11);
    for (int idx = t; idx < 2048; idx += 512)
        if (idx < limit) rowptr8[(b << 11) + idx] = base + lsc[idx];
    for (int i = 0; i < nh; i++) {
        int p = base + lsc[key[i]] + rank[i];
        edata[p] = make_int2(held[i].x & 0xFFFFF, held[i].y);   // src | et<<17
    }
}

// ---------------- size matcher (MFMA, no LDS)
__launch_bounds__(256)
__global__ void k_sizematch(const int* __restrict__ feat, const float* __restrict__ emb_w,
                            const unsigned short* __restrict__ smPack, const float* __restrict__ sm_b,
                            unsigned short* __restrict__ xb) {
    int t = threadIdx.x;
    int wave = t >> 6, lane = t & 63;
    int q = lane >> 4, c = lane & 15;
    int n0 = blockIdx.x * 64 + wave * 16;
    int node = n0 + c;
    int nclamp = (node < N_NODES) ? node : (N_NODES - 1);
    const int4* fr = (const int4*)(feat + (size_t)nclamp * 8);
    int4 f0 = fr[0], f1 = fr[1];
    int fidx[8] = {f0.x, f0.y, f0.z, f0.w, f1.x, f1.y, f1.z, f1.w};
    f32x4 acc[4];
#pragma unroll
    for (int i = 0; i < 4; i++) acc[i] = (f32x4){0.f, 0.f, 0.f, 0.f};
    const bf16x8* B8 = (const bf16x8*)smPack;
#pragma unroll
    for (int s = 0; s < 8; s++) {
        const float4* ar = (const float4*)(emb_w + (size_t)fidx[s] * 32 + q * 8);
        float4 a0 = ar[0], a1 = ar[1];
        union { unsigned u[4]; bf16x8 v; } A;
        A.u[0] = packtrunc(a0.x, a0.y);
        A.u[1] = packtrunc(a0.z, a0.w);
        A.u[2] = packtrunc(a1.x, a1.y);
        A.u[3] = packtrunc(a1.z, a1.w);
#pragma unroll
        for (int tl = 0; tl < 4; tl++) {
            bf16x8 b = B8[(s * 4 + q) * 64 + tl * 16 + c];
            acc[tl] = __builtin_amdgcn_mfma_f32_16x16x32_bf16(A.v, b, acc[tl], 0, 0, 0);
        }
    }
    int row_base = n0 + q * 4;
    bool full = (n0 + 15 < N_NODES);
#pragma unroll
    for (int tl = 0; tl < 4; tl++) {
        int o = tl * 16 + c;
        float bia = sm_b[o];
#pragma unroll
        for (int r = 0; r < 4; r++) {
            int nd = row_base + r;
            if (full || nd < N_NODES)
                xb[(size_t)nd * 64 + o] = f2bf(acc[tl][r] + bia);
        }
    }
}

// ---------------- fused layer: rel-sorted flush aggregation (scalarized) + MFMA
// block: 256 thr = 4 waves; 16 nodes/block (4 per wave); grid N_NODES/16.
// Edge fields are wave-uniform -> readfirstlane makes flush branch scalar and
// gather a scalar-base load with loop-invariant lane offset.
__launch_bounds__(256)
__global__ void k_fused(const unsigned short* __restrict__ xin,
                        const int* __restrict__ rowptr8, const int2* __restrict__ edata,
                        const unsigned short* __restrict__ WpF, const float* __restrict__ bias,
                        float* __restrict__ outf, unsigned short* __restrict__ outb, int mode) {
    __shared__ __align__(16) unsigned short agg[16 * 520];
    int t = threadIdx.x;
    int wave = t >> 6, lane = t & 63;
    int n0 = blockIdx.x * 16;
    {
        int* a4 = (int*)agg;
        for (int i = t; i < 16 * 260; i += 256) a4[i] = 0;
    }
    __syncthreads();
    for (int ni = 0; ni < 4; ni++) {
        int lrow = wave * 4 + ni;
        int node = n0 + lrow;
        int j0 = rowptr8[(size_t)node * 8];
        int j1 = rowptr8[(size_t)node * 8 + 8];
        float acc = 0.f;
        int curR = 0;
        int j = j0;
        for (; j + 4 <= j1; j += 4) {
            int2 e0 = edata[j], e1 = edata[j + 1], e2 = edata[j + 2], e3 = edata[j + 3];
            int x0 = __builtin_amdgcn_readfirstlane(e0.x);
            int y0 = __builtin_amdgcn_readfirstlane(e0.y);
            int x1 = __builtin_amdgcn_readfirstlane(e1.x);
            int y1 = __builtin_amdgcn_readfirstlane(e1.y);
            int x2 = __builtin_amdgcn_readfirstlane(e2.x);
            int y2 = __builtin_amdgcn_readfirstlane(e2.y);
            int x3 = __builtin_amdgcn_readfirstlane(e3.x);
            int y3 = __builtin_amdgcn_readfirstlane(e3.y);
            const unsigned short* p0 = xin + ((size_t)(x0 & 0x1FFFF) << 6);
            const unsigned short* p1 = xin + ((size_t)(x1 & 0x1FFFF) << 6);
            const unsigned short* p2 = xin + ((size_t)(x2 & 0x1FFFF) << 6);
            const unsigned short* p3 = xin + ((size_t)(x3 & 0x1FFFF) << 6);
            unsigned short v0 = p0[lane];
            unsigned short v1 = p1[lane];
            unsigned short v2 = p2[lane];
            unsigned short v3 = p3[lane];
            int et0 = (x0 >> 17) & 7;
            if (et0 != curR) { agg[lrow * 520 + curR * 64 + lane] = f2bf(acc); acc = 0.f; curR = et0; }
            acc = fmaf(__int_as_float(y0), bf2f(v0), acc);
            int et1 = (x1 >> 17) & 7;
            if (et1 != curR) { agg[lrow * 520 + curR * 64 + lane] = f2bf(acc); acc = 0.f; curR = et1; }
            acc = fmaf(__int_as_float(y1), bf2f(v1), acc);
            int et2 = (x2 >> 17) & 7;
            if (et2 != curR) { agg[lrow * 520 + curR * 64 + lane] = f2bf(acc); acc = 0.f; curR = et2; }
            acc = fmaf(__int_as_float(y2), bf2f(v2), acc);
            int et3 = (x3 >> 17) & 7;
            if (et3 != curR) { agg[lrow * 520 + curR * 64 + lane] = f2bf(acc); acc = 0.f; curR = et3; }
            acc = fmaf(__int_as_float(y3), bf2f(v3), acc);
        }
        for (; j < j1; j++) {
            int2 e = edata[j];
            int x = __builtin_amdgcn_readfirstlane(e.x);
            int y = __builtin_amdgcn_readfirstlane(e.y);
            const unsigned short* pp = xin + ((size_t)(x & 0x1FFFF) << 6);
            unsigned short v = pp[lane];
            int et = (x >> 17) & 7;
            if (et != curR) { agg[lrow * 520 + curR * 64 + lane] = f2bf(acc); acc = 0.f; curR = et; }
            acc = fmaf(__int_as_float(y), bf2f(v), acc);
        }
        agg[lrow * 520 + curR * 64 + lane] = f2bf(acc);
    }
    __syncthreads();
    // ---- MFMA: [16 nodes x 512] @ WpF -> 64 outs; wave covers cols [wave*16, +16)
    int q = lane >> 4, c = lane & 15;
    int o16 = wave * 16;
    f32x4 accd = (f32x4){0.f, 0.f, 0.f, 0.f};
    const bf16x8* B8 = (const bf16x8*)WpF;
#pragma unroll
    for (int s = 0; s < 16; s++) {
        bf16x8 a = *(const bf16x8*)&agg[c * 520 + s * 32 + q * 8];
        bf16x8 bfr = B8[(s * 4 + q) * 64 + o16 + c];
        accd = __builtin_amdgcn_mfma_f32_16x16x32_bf16(a, bfr, accd, 0, 0, 0);
    }
    int col = o16 + c;
    float bia = bias[col];
#pragma unroll
    for (int r = 0; r < 4; r++) {
        int node = n0 + q * 4 + r;
        float v = accd[r] + bia;
        if (mode == 1) {
            v = fmaxf(v, 0.f);
            outb[(size_t)node * 64 + col] = f2bf(v);
        } else {
            outf[(size_t)node * 64 + col] = v;
        }
    }
}

extern "C" void kernel_launch(void* const* d_in, const int* in_sizes, int n_in,
                              void* d_out, int out_size, void* d_ws, size_t ws_size,
                              hipStream_t stream) {
    const int*   feat  = (const int*)d_in[0];
    const int*   src   = (const int*)d_in[1];
    const int*   dst   = (const int*)d_in[2];
    const int*   etype = (const int*)d_in[3];
    const float* norm  = (const float*)d_in[4];
    const float* emb_w = (const float*)d_in[5];
    const float* sm_w  = (const float*)d_in[6];
    const float* sm_b  = (const float*)d_in[7];
    const float* V1    = (const float*)d_in[8];
    const float* comp1 = (const float*)d_in[9];
    const float* b1    = (const float*)d_in[10];
    const float* V2    = (const float*)d_in[11];
    const float* comp2 = (const float*)d_in[12];
    const float* b2    = (const float*)d_in[13];
    float* out = (float*)d_out;

    char* p = (char*)d_ws;
    auto alloc = [&](size_t bytes) { void* q = (void*)p; p += (bytes + 255) & ~(size_t)255; return q; };
    unsigned short* xb   = (unsigned short*)alloc((size_t)N_PAD * 64 * 2);  // 12.8 MB
    unsigned short* hb   = (unsigned short*)alloc((size_t)N_PAD * 64 * 2);  // 12.8 MB
    unsigned short* WpF1 = (unsigned short*)alloc((size_t)KF * HD * 2);     // 64 KB
    unsigned short* WpF2 = (unsigned short*)alloc((size_t)KF * HD * 2);
    unsigned short* smPack = (unsigned short*)alloc(KDIM * HD * 2);         // 32 KB
    int*   cnt    = (int*)alloc((size_t)NBLK_P * NBUCK * 4);                // 803 KB
    int*   boffm  = (int*)alloc((size_t)NBLK_P * NBUCK * 4);                // 803 KB
    int*   btot   = (int*)alloc((size_t)NBUCK * 4);
    int*   bstart = (int*)alloc((size_t)(NBUCK + 1) * 4);
    int*   rowptr8 = (int*)alloc(((size_t)N_NODES * 8 + 1) * 4);            // 3.2 MB
    int2*  staged = (int2*)alloc((size_t)N_EDGES * 8);                      // 12.8 MB
    int2*  edata  = (int2*)alloc((size_t)N_EDGES * 8);                      // 12.8 MB

    k_weights<<<320, 256, 0, stream>>>(V1, comp1, V2, comp2, sm_w, WpF1, WpF2, smPack);

    k_pcount<<<NBLK_P, TPB_P, 0, stream>>>(dst, cnt);
    k_pscan<<<NBUCK_USED, NBLK_P, 0, stream>>>(cnt, boffm, btot);
    k_bscan<<<1, 512, 0, stream>>>(btot, bstart, rowptr8);
    k_pscatter<<<NBLK_P, TPB_P, 0, stream>>>(src, dst, etype, norm, boffm, bstart, staged);
    k_finalize<<<NBUCK_USED, 512, 0, stream>>>(staged, bstart, btot, rowptr8, edata);

    k_sizematch<<<N_PAD / 64, 256, 0, stream>>>(feat, emb_w, smPack, sm_b, xb);

    k_fused<<<N_NODES / 16, 256, 0, stream>>>(xb, rowptr8, edata, WpF1, b1, nullptr, hb, 1);
    k_fused<<<N_NODES / 16, 256, 0, stream>>>(hb, rowptr8, edata, WpF2, b2, out, nullptr, 0);
}